// Round 11
// baseline (355.792 us; speedup 1.0000x reference)
//
#include <hip/hip_runtime.h>

typedef unsigned short u16;
typedef unsigned int u32;
typedef __attribute__((ext_vector_type(8))) short bf16x8;
typedef __attribute__((ext_vector_type(4))) float f32x4;

#define NN 20000      // real nodes
#define NE 320000     // edges
#define NPAD 20032    // nodes padded (x64)
#define D 64
#define R 4
#define NG 128
#define NC 16
#define NL 4
#define MROWS (NN*R)         // BN divisor (real rows only)
#define NTILE (NPAD/32)      // 626 node-tiles of 32 per run
#define HTILE (NTILE/2)      // 313
#define NBLKF (R*NTILE)      // 2504 fgg blocks (1 run x 32 nodes each)
#define NBLKG (R*NPAD/64)    // 1252 gemm blocks (64 rows each)
#define NPART NBLKF
#define NPOOL (4*NG)         // 512 pool blocks
#define EPAD 480256          // padded edge slots (>= NE + 4*NN)
#define BN_EPS 1e-5f

__device__ __forceinline__ float bf2f(u16 v) {
    union { u32 u; float f; } c; c.u = ((u32)v) << 16; return c.f;
}
__device__ __forceinline__ u16 f2bf(float f) {
    union { u32 u; float f; } c; c.f = f;
    u32 u = c.u;
    return (u16)((u + 0x7fffu + ((u >> 16) & 1u)) >> 16);   // RNE
}
// swizzled u16 index into a [rows][64] bf16 LDS tile
__device__ __forceinline__ int swz(int row, int kbyte) {
    return row * 64 + (((kbyte) ^ ((row & 7) << 4)) >> 1);
}

// ---------------- setup: H0 = masked bf16 x (RUN-major [r][n][64]), esrc fill,
//                  deg zero, pooled zero ----------------
__global__ void k_setup(const float* __restrict__ x, const int* __restrict__ mask,
                        u16* __restrict__ H, int* __restrict__ esrc, int* __restrict__ deg,
                        float* __restrict__ pooled) {
    int id = blockIdx.x * 256 + threadIdx.x;
    if (id < EPAD) esrc[id] = NN;          // dummy -> zero row (pad node NN stays 0)
    if (id < NPAD) deg[id] = 0;
    if (id < 5 * NG * 64) pooled[id] = 0.f;
    if (id < R * NPAD * 16) {              // quads: r, n, q
        int r = id / (NPAD * 16);
        int rem = id - r * (NPAD * 16);
        int n = rem >> 4, q = rem & 15;
        ushort4 o; o.x = o.y = o.z = o.w = 0;
        if (n < NN && mask[r * NN + n] == 0) {
            float4 v = *(const float4*)(x + (size_t)n * 64 + q * 4);
            o.x = f2bf(v.x); o.y = f2bf(v.y); o.z = f2bf(v.z); o.w = f2bf(v.w);
        }
        *(ushort4*)(H + ((size_t)r * NPAD + n) * 64 + q * 4) = o;
    }
}

// ---------------- CSR build ----------------
__global__ void k_deg(const int* __restrict__ dst, int* __restrict__ deg) {
    int e = blockIdx.x * 256 + threadIdx.x;
    if (e < NE) atomicAdd(&deg[dst[e]], 1);
}

// scan of (deg+1 self) padded to x4; writes self edge into first slot
__global__ __launch_bounds__(1024) void k_scan(const int* __restrict__ deg,
                                               int* __restrict__ rowstart,
                                               int* __restrict__ cursor,
                                               int* __restrict__ esrc) {
    __shared__ int wsum[16];
    __shared__ int woff[16];
    __shared__ int carry_s, chunktot;
    const int t = threadIdx.x, lane = t & 63, wv = t >> 6;
    if (t == 0) carry_s = 0;
    __syncthreads();
    for (int base = 0; base < NPAD; base += 1024) {
        int i = base + t;
        int v = (i < NN) ? ((deg[i] + 4) & ~3) : 0;   // (deg+1self) padded to x4
        int x = v;
#pragma unroll
        for (int off = 1; off < 64; off <<= 1) {
            int y = __shfl_up(x, off);
            if (lane >= off) x += y;
        }
        if (lane == 63) wsum[wv] = x;
        __syncthreads();
        if (t < 16) {
            int s = wsum[t], sx = s;
#pragma unroll
            for (int off = 1; off < 16; off <<= 1) {
                int y = __shfl_up(sx, off);
                if (t >= off) sx += y;
            }
            woff[t] = sx - s;
            if (t == 15) chunktot = sx;
        }
        __syncthreads();
        int excl = carry_s + woff[wv] + x - v;
        if (i < NPAD) rowstart[i] = excl;
        if (i < NN) { esrc[excl] = i; cursor[i] = excl + 1; }   // self slot
        __syncthreads();
        if (t == 0) carry_s += chunktot;
        __syncthreads();
    }
    if (t == 0) rowstart[NPAD] = carry_s;
}

__global__ void k_fill(const int* __restrict__ src, const int* __restrict__ dst,
                       int* __restrict__ cursor, int* __restrict__ esrc) {
    int e = blockIdx.x * 256 + threadIdx.x;
    if (e < NE) {
        int p = atomicAdd(&cursor[dst[e]], 1);
        esrc[p] = src[e];
    }
}

// ---------------- fused gather + MFMA-GEMM1 + stat partials (run-XCD-affine) ----
// block -> (run, 32 nodes) via xcd = blk&7, run = xcd&3: each XCD touches ONE
// 2.56MB run slice (fits 4MB per-XCD L2). Lane group g (lane>>4) handles slot
// k+g; per 8 slots: 2 idx loads + 2 ushort4 row loads + ~16 VALU.
__global__ __launch_bounds__(256) void k_fgg(const u16* __restrict__ Z,
                                             u16* __restrict__ Y,
                                             const int* __restrict__ rowstart,
                                             const int* __restrict__ esrc,
                                             const float* __restrict__ W,
                                             const float* __restrict__ bias,
                                             float* __restrict__ part) {
    __shared__ __align__(16) u16 Xs[32 * 64];     // 4 KB
    __shared__ __align__(16) u16 Wt[64 * 64];     // 8 KB
    __shared__ float red[128];
    const int t = threadIdx.x, lane = t & 63, wv = t >> 6;
    const int blk = blockIdx.x;
    const int xcd = blk & 7;
    const int run = xcd & 3;
    const int node0 = ((blk >> 3) + HTILE * (xcd >> 2)) * 32;
    const u16* Zr = Z + (size_t)run * (NPAD * 64);

    {   // stage Wt[n][k] = bf16(W[k][n]) swizzled
        int k = t >> 2, cb = (t & 3) * 16;
        const float* Wp = W + k * 64 + cb;
        float4 v0 = *(const float4*)Wp;
        float4 v1 = *(const float4*)(Wp + 4);
        float4 v2 = *(const float4*)(Wp + 8);
        float4 v3 = *(const float4*)(Wp + 12);
        float vv[16] = {v0.x, v0.y, v0.z, v0.w, v1.x, v1.y, v1.z, v1.w,
                        v2.x, v2.y, v2.z, v2.w, v3.x, v3.y, v3.z, v3.w};
#pragma unroll
        for (int j = 0; j < 16; j++) Wt[swz(cb + j, k * 2)] = f2bf(vv[j]);
    }

    // ---- gather: wave does 8 nodes; lane: slot-group g, cols cl..cl+3 ----
    const int g = lane >> 4, cl = (lane & 15) * 4;
    for (int i = 0; i < 8; i++) {
        const int n = node0 + wv * 8 + i;
        float a0 = 0.f, a1 = 0.f, a2 = 0.f, a3 = 0.f;
        int s0 = __builtin_amdgcn_readfirstlane(rowstart[n]);
        int s1 = __builtin_amdgcn_readfirstlane(rowstart[n + 1]);
#define ACC(v) { a0 += bf2f(v.x); a1 += bf2f(v.y); a2 += bf2f(v.z); a3 += bf2f(v.w); }
        int k = s0;
        for (; k + 8 <= s1; k += 8) {
            int e0 = esrc[k + g];
            int e1 = esrc[k + 4 + g];
            ushort4 va = *(const ushort4*)(Zr + (size_t)e0 * 64 + cl);
            ushort4 vb = *(const ushort4*)(Zr + (size_t)e1 * 64 + cl);
            ACC(va) ACC(vb)
        }
        if (k < s1) {   // exactly 4 remaining (padded to x4)
            int e0 = esrc[k + g];
            ushort4 va = *(const ushort4*)(Zr + (size_t)e0 * 64 + cl);
            ACC(va)
        }
#undef ACC
        // reduce across the 4 slot-groups
        a0 += __shfl_xor(a0, 16); a0 += __shfl_xor(a0, 32);
        a1 += __shfl_xor(a1, 16); a1 += __shfl_xor(a1, 32);
        a2 += __shfl_xor(a2, 16); a2 += __shfl_xor(a2, 32);
        a3 += __shfl_xor(a3, 16); a3 += __shfl_xor(a3, 32);
        if (g == 0) {
            const int lrow = wv * 8 + i;
            u32 lo = (u32)f2bf(a0) | ((u32)f2bf(a1) << 16);
            u32 hi = (u32)f2bf(a2) | ((u32)f2bf(a3) << 16);
            *(uint2*)&Xs[swz(lrow, cl * 2)] = make_uint2(lo, hi);
        }
    }
    __syncthreads();

    // ---- MFMA: wave = col block wv; both 16-row halves ----
    const int l15 = lane & 15, l4 = lane >> 4;
    const int col = wv * 16 + l15;
    bf16x8 a00 = *(bf16x8*)&Xs[swz(l15, l4 * 16)];
    bf16x8 a01 = *(bf16x8*)&Xs[swz(l15, 64 + l4 * 16)];
    bf16x8 a10 = *(bf16x8*)&Xs[swz(16 + l15, l4 * 16)];
    bf16x8 a11 = *(bf16x8*)&Xs[swz(16 + l15, 64 + l4 * 16)];
    bf16x8 bf0 = *(bf16x8*)&Wt[swz(col, l4 * 16)];
    bf16x8 bf1 = *(bf16x8*)&Wt[swz(col, 64 + l4 * 16)];
    float bv = bias[col];
    f32x4 acc0 = (f32x4){bv, bv, bv, bv};
    f32x4 acc1 = acc0;
    acc0 = __builtin_amdgcn_mfma_f32_16x16x32_bf16(a00, bf0, acc0, 0, 0, 0);
    acc0 = __builtin_amdgcn_mfma_f32_16x16x32_bf16(a01, bf1, acc0, 0, 0, 0);
    acc1 = __builtin_amdgcn_mfma_f32_16x16x32_bf16(a10, bf0, acc1, 0, 0, 0);
    acc1 = __builtin_amdgcn_mfma_f32_16x16x32_bf16(a11, bf1, acc1, 0, 0, 0);

    const size_t ybase = ((size_t)run * NPAD + node0) * 64;
    float s = 0.f, q = 0.f;
#pragma unroll
    for (int j = 0; j < 4; j++) {
        int row0 = l4 * 4 + j, row1 = 16 + l4 * 4 + j;
        __builtin_nontemporal_store(f2bf(acc0[j]), &Y[ybase + (size_t)row0 * 64 + col]);
        __builtin_nontemporal_store(f2bf(acc1[j]), &Y[ybase + (size_t)row1 * 64 + col]);
        float m0 = (node0 + row0 < NN) ? 1.f : 0.f;
        float m1 = (node0 + row1 < NN) ? 1.f : 0.f;
        float v0 = m0 * acc0[j], v1 = m1 * acc1[j];
        s += v0 + v1;
        q += v0 * acc0[j] + v1 * acc1[j];
    }
    s += __shfl_xor(s, 16); s += __shfl_xor(s, 32);
    q += __shfl_xor(q, 16); q += __shfl_xor(q, 32);
    if (l4 == 0) {
        red[wv * 32 + l15] = s;
        red[wv * 32 + 16 + l15] = q;
    }
    __syncthreads();
    if (t < 128) {
        int c = (t < 64) ? t : (t - 64);
        int off = (t < 64) ? 0 : 16;
        part[(size_t)t * NPART + blk] = red[(c >> 4) * 32 + off + (c & 15)];
    }
}

// ---------------- GEMM2: BN+ReLU staging, MFMA, stat partials (64-row blocks) ----
__global__ __launch_bounds__(256) void k_gemm(const u16* __restrict__ Pin,
                                              u16* __restrict__ Qout,
                                              const float* __restrict__ W,
                                              const float* __restrict__ bias,
                                              const float* __restrict__ inStats,
                                              const float* __restrict__ gamma,
                                              const float* __restrict__ beta,
                                              float* __restrict__ part) {
    __shared__ __align__(16) u16 Xs[64 * 64];
    __shared__ __align__(16) u16 Wt[64 * 64];
    __shared__ float red[512];
    __shared__ float Psc[64], Psh[64];
    const int t = threadIdx.x, lane = t & 63, wv = t >> 6;
    const int blk = blockIdx.x;
    const int rblk = blk / (NPAD / 64);               // run
    const int n0 = (blk % (NPAD / 64)) * 64;          // node base

    {   // stage Wt
        int k = t >> 2, cb = (t & 3) * 16;
        const float* Wp = W + k * 64 + cb;
        float4 v0 = *(const float4*)Wp;
        float4 v1 = *(const float4*)(Wp + 4);
        float4 v2 = *(const float4*)(Wp + 8);
        float4 v3 = *(const float4*)(Wp + 12);
        float vv[16] = {v0.x, v0.y, v0.z, v0.w, v1.x, v1.y, v1.z, v1.w,
                        v2.x, v2.y, v2.z, v2.w, v3.x, v3.y, v3.z, v3.w};
#pragma unroll
        for (int j = 0; j < 16; j++) Wt[swz(cb + j, k * 2)] = f2bf(vv[j]);
    }
    if (t < 64) {
        float m = inStats[t] * (1.0f / MROWS);
        float var = inStats[64 + t] * (1.0f / MROWS) - m * m;
        float sc = gamma[t] * rsqrtf(var + BN_EPS);
        Psc[t] = sc;
        Psh[t] = beta[t] - m * sc;
    }
    __syncthreads();

    const int row = t >> 2, cb = (t & 3) * 16;
    const size_t base = ((size_t)rblk * NPAD + n0) * 64;
    {   // stage X, affine+relu, bf16, swizzled
        const u16* Xp = Pin + base + (size_t)row * 64 + cb;
        uint4 a = *(const uint4*)Xp;
        uint4 bq = *(const uint4*)(Xp + 8);
        u32 w[8] = {a.x, a.y, a.z, a.w, bq.x, bq.y, bq.z, bq.w};
        u32 ow[8];
#pragma unroll
        for (int j = 0; j < 8; j++) {
            int c = cb + 2 * j;
            union { u32 u; float f; } lo, hi;
            lo.u = w[j] << 16;
            hi.u = w[j] & 0xffff0000u;
            float v0 = fmaxf(fmaf(lo.f, Psc[c], Psh[c]), 0.f);
            float v1 = fmaxf(fmaf(hi.f, Psc[c + 1], Psh[c + 1]), 0.f);
            ow[j] = (u32)f2bf(v0) | ((u32)f2bf(v1) << 16);
        }
        *(uint4*)&Xs[swz(row, cb * 2)] = make_uint4(ow[0], ow[1], ow[2], ow[3]);
        *(uint4*)&Xs[swz(row, cb * 2 + 16)] = make_uint4(ow[4], ow[5], ow[6], ow[7]);
    }
    __syncthreads();

    const int l4 = lane >> 4, l15 = lane & 15;
    const int arow = wv * 16 + l15;
    bf16x8 af0 = *(bf16x8*)&Xs[swz(arow, l4 * 16)];
    bf16x8 af1 = *(bf16x8*)&Xs[swz(arow, 64 + l4 * 16)];
    f32x4 acc[4];
#pragma unroll
    for (int nb = 0; nb < 4; nb++) {
        int n = nb * 16 + l15;
        float bv = bias[n];
        acc[nb] = (f32x4){bv, bv, bv, bv};
        bf16x8 bf0 = *(bf16x8*)&Wt[swz(n, l4 * 16)];
        bf16x8 bf1 = *(bf16x8*)&Wt[swz(n, 64 + l4 * 16)];
        acc[nb] = __builtin_amdgcn_mfma_f32_16x16x32_bf16(af0, bf0, acc[nb], 0, 0, 0);
        acc[nb] = __builtin_amdgcn_mfma_f32_16x16x32_bf16(af1, bf1, acc[nb], 0, 0, 0);
    }

#pragma unroll
    for (int nb = 0; nb < 4; nb++) {
        int col = nb * 16 + l15;
#pragma unroll
        for (int j = 0; j < 4; j++) {
            int lrow = wv * 16 + l4 * 4 + j;
            __builtin_nontemporal_store(f2bf(acc[nb][j]),
                                        &Qout[base + (size_t)lrow * 64 + col]);
        }
    }

#pragma unroll
    for (int nb = 0; nb < 4; nb++) {
        float s = 0.f, q = 0.f;
#pragma unroll
        for (int j = 0; j < 4; j++) {
            int lrow = wv * 16 + l4 * 4 + j;
            float vm = (n0 + lrow < NN) ? 1.f : 0.f;
            float v = vm * acc[nb][j];
            s += v; q += v * acc[nb][j];
        }
        s += __shfl_xor(s, 16); s += __shfl_xor(s, 32);
        q += __shfl_xor(q, 16); q += __shfl_xor(q, 32);
        if (l4 == 0) {
            red[wv * 128 + nb * 16 + l15] = s;
            red[wv * 128 + 64 + nb * 16 + l15] = q;
        }
    }
    __syncthreads();
    if (t < 128) {
        float v = red[t] + red[128 + t] + red[256 + t] + red[384 + t];
        part[(size_t)t * NPART + blk] = v;
    }
}

// ---------------- reduce stat partials ----------------
__global__ __launch_bounds__(256) void k_statreduce(const float* __restrict__ part,
                                                    float* __restrict__ stats, int count) {
    const int j = blockIdx.x, t = threadIdx.x;
    float s = 0.f;
    for (int p = t; p < count; p += 256) s += part[(size_t)j * NPART + p];
#pragma unroll
    for (int off = 32; off > 0; off >>= 1) s += __shfl_xor(s, off);
    __shared__ float red[4];
    if ((t & 63) == 0) red[t >> 6] = s;
    __syncthreads();
    if (t == 0) stats[j] = red[0] + red[1] + red[2] + red[3];
}

// ---------------- pool: block = (graph, run); BN+ReLU + H materialization ----------------
// (gr*4+r)%8 puts run r on XCDs {r, r+4} — same mapping as k_fgg.
template <bool APPLY>
__global__ __launch_bounds__(256) void k_pool(const u16* __restrict__ Zin,
                                              const int* __restrict__ batch,
                                              float* __restrict__ pooled,
                                              u16* __restrict__ Hout,
                                              const float* __restrict__ stats,
                                              const float* __restrict__ g,
                                              const float* __restrict__ b) {
    const int blk = blockIdx.x;
    const int gr = blk >> 2, r = blk & 3;
    const int t = threadIdx.x;
    int lo = 0, hi = NN;
    while (lo < hi) { int mid = (lo + hi) >> 1; if (batch[mid] < gr) lo = mid + 1; else hi = mid; }
    const int start = lo;
    lo = 0; hi = NN;
    while (lo < hi) { int mid = (lo + hi) >> 1; if (batch[mid] < gr + 1) lo = mid + 1; else hi = mid; }
    const int end = lo;

    const int grp = t >> 4;           // 0..15 node stride
    const int cl = (t & 15) * 4;
    const u16* Zr = Zin + (size_t)r * (NPAD * 64);
    u16* Hr = Hout + (size_t)r * (NPAD * 64);
    float sc[4], sh[4];
    if (APPLY) {
#pragma unroll
        for (int j = 0; j < 4; j++) {
            int c = cl + j;
            float m = stats[c] * (1.f / MROWS);
            float var = stats[64 + c] * (1.f / MROWS) - m * m;
            float s = g[c] * rsqrtf(var + BN_EPS);
            sc[j] = s;
            sh[j] = b[c] - m * s;
        }
    }
    float a0 = 0.f, a1 = 0.f, a2 = 0.f, a3 = 0.f;
#define PBODY(nn)                                                              \
    {                                                                          \
        ushort4 v = *(const ushort4*)(Zr + (size_t)(nn) * 64 + cl);            \
        float f0 = bf2f(v.x), f1 = bf2f(v.y), f2 = bf2f(v.z), f3 = bf2f(v.w);  \
        if (APPLY) {                                                           \
            f0 = fmaxf(fmaf(f0, sc[0], sh[0]), 0.f);                           \
            f1 = fmaxf(fmaf(f1, sc[1], sh[1]), 0.f);                           \
            f2 = fmaxf(fmaf(f2, sc[2], sh[2]), 0.f);                           \
            f3 = fmaxf(fmaf(f3, sc[3], sh[3]), 0.f);                           \
            ushort4 o;                                                         \
            o.x = f2bf(f0); o.y = f2bf(f1); o.z = f2bf(f2); o.w = f2bf(f3);    \
            *(ushort4*)(Hr + (size_t)(nn) * 64 + cl) = o;                      \
        }                                                                      \
        a0 += f0; a1 += f1; a2 += f2; a3 += f3;                                \
    }
    int n = start + grp;
    for (; n + 16 < end; n += 32) { PBODY(n); PBODY(n + 16); }
    for (; n < end; n += 16) PBODY(n);
#undef PBODY
    __shared__ float red[16 * 64];
    red[grp * 64 + cl + 0] = a0;
    red[grp * 64 + cl + 1] = a1;
    red[grp * 64 + cl + 2] = a2;
    red[grp * 64 + cl + 3] = a3;
    __syncthreads();
    if (t < 64) {
        float s = 0.f;
#pragma unroll
        for (int k = 0; k < 16; k++) s += red[k * 64 + t];
        atomicAdd(&pooled[gr * 64 + t], 0.25f * s);
    }
}

// ---------------- readout ----------------
__global__ __launch_bounds__(256) void k_readout(const float* __restrict__ pooled,
                                                 const float* __restrict__ fcW,
                                                 const float* __restrict__ fcb,
                                                 float* __restrict__ out) {
    const int gr = blockIdx.x, t = threadIdx.x;
    const int c = t & 15, seg = t >> 4;
    float acc = 0.f;
#pragma unroll
    for (int i = 0; i < 5; i++)
#pragma unroll
        for (int k = 0; k < 4; k++) {
            int d = seg * 4 + k;
            acc = fmaf(pooled[i * (NG * D) + gr * D + d], fcW[i * 1024 + d * 16 + c], acc);
        }
    __shared__ float red[16][17];
    red[seg][c] = acc;
    __syncthreads();
    if (t < 16) {
        float s = 0.f;
#pragma unroll
        for (int s2 = 0; s2 < 16; s2++) s += red[s2][t];
#pragma unroll
        for (int i = 0; i < 5; i++) s += fcb[i * NC + t];
        float mx = s;
#pragma unroll
        for (int m = 1; m < 16; m <<= 1) mx = fmaxf(mx, __shfl_xor(mx, m));
        float e = expf(s - mx), se = e;
#pragma unroll
        for (int m = 1; m < 16; m <<= 1) se += __shfl_xor(se, m);
        out[gr * NC + t] = s - mx - logf(se);
    }
}

extern "C" void kernel_launch(void* const* d_in, const int* in_sizes, int n_in,
                              void* d_out, int out_size, void* d_ws, size_t ws_size,
                              hipStream_t stream) {
    const float* x = (const float*)d_in[0];
    const int* ei = (const int*)d_in[1];
    const int* srcp = ei;
    const int* dstp = ei + NE;
    const int* batch = (const int*)d_in[2];
    const int* mask = (const int*)d_in[3];
    const float* convW1 = (const float*)d_in[4];
    const float* convb1 = (const float*)d_in[5];
    const float* mlp_bn_g = (const float*)d_in[6];
    const float* mlp_bn_b = (const float*)d_in[7];
    const float* convW2 = (const float*)d_in[8];
    const float* convb2 = (const float*)d_in[9];
    const float* bn_g = (const float*)d_in[10];
    const float* bn_b = (const float*)d_in[11];
    const float* fcW = (const float*)d_in[12];
    const float* fcb = (const float*)d_in[13];
    float* out = (float*)d_out;

    u16* H = (u16*)d_ws;                       // [R][NPAD][64] bf16 (pad rows stay zero)
    u16* P = H + (size_t)R * NPAD * 64;
    u16* Q = P + (size_t)R * NPAD * 64;
    float* pooled = (float*)(Q + (size_t)R * NPAD * 64);   // [5][NG][64]
    float* stats = pooled + 5 * NG * D;        // [NL][2][128]
    float* part = stats + NL * 2 * 128;        // [128][NPART]
    int* rowstart = (int*)(part + 128 * NPART);  // [NPAD+1]
    int* cursor = rowstart + NPAD + 1;           // [NN]
    int* deg = cursor + NPAD;                    // [NPAD]
    int* esrc = deg + NPAD;                      // [EPAD]

    k_setup<<<(R * NPAD * 16 + 255) / 256, 256, 0, stream>>>(x, mask, H, esrc, deg, pooled);
    k_deg<<<(NE + 255) / 256, 256, 0, stream>>>(dstp, deg);
    k_scan<<<1, 1024, 0, stream>>>(deg, rowstart, cursor, esrc);
    k_fill<<<(NE + 255) / 256, 256, 0, stream>>>(srcp, dstp, cursor, esrc);

    k_pool<false><<<NPOOL, 256, 0, stream>>>(H, batch, pooled, nullptr,
                                             nullptr, nullptr, nullptr);

    for (int i = 0; i < NL; i++) {
        float* st1 = stats + (i * 2 + 0) * 128;
        float* st2 = stats + (i * 2 + 1) * 128;
        k_fgg<<<NBLKF, 256, 0, stream>>>(H, P, rowstart, esrc,
                                         convW1 + i * 4096, convb1 + i * 64, part);
        k_statreduce<<<128, 256, 0, stream>>>(part, st1, NBLKF);
        k_gemm<<<NBLKG, 256, 0, stream>>>(P, Q, convW2 + i * 4096, convb2 + i * 64,
                                          st1, mlp_bn_g + i * 64, mlp_bn_b + i * 64, part);
        k_statreduce<<<128, 256, 0, stream>>>(part, st2, NBLKG);
        k_pool<true><<<NPOOL, 256, 0, stream>>>(Q, batch, pooled + (i + 1) * (NG * D), H,
                                                st2, bn_g + i * 64, bn_b + i * 64);
    }

    k_readout<<<NG, 256, 0, stream>>>(pooled, fcW, fcb, out);
}

// Round 12
// 324.265 us; speedup vs baseline: 1.0972x; 1.0972x over previous
//
#include <hip/hip_runtime.h>

typedef unsigned short u16;
typedef unsigned int u32;
typedef __attribute__((ext_vector_type(8))) short bf16x8;
typedef __attribute__((ext_vector_type(4))) float f32x4;

#define NN 20000      // real nodes
#define NE 320000     // edges
#define NPAD 20032    // nodes padded (x64)
#define D 64
#define R 4
#define NG 128
#define NC 16
#define NL 4
#define MROWS (NN*R)         // BN divisor (real rows only)
#define NTILE (NPAD/32)      // 626 node-tiles of 32 per run
#define HTILE (NTILE/2)      // 313
#define NBLKF (R*NTILE)      // 2504 fgg blocks (1 run x 32 nodes each)
#define NBLKG (R*NPAD/64)    // 1252 gemm blocks (64 rows each)
#define NPART NBLKF
#define NPOOL (4*NG)         // 512 pool blocks
#define EPAD 480256          // padded edge slots (>= NE + 4*NN)
#define BN_EPS 1e-5f

__device__ __forceinline__ float bf2f(u16 v) {
    union { u32 u; float f; } c; c.u = ((u32)v) << 16; return c.f;
}
__device__ __forceinline__ u16 f2bf(float f) {
    union { u32 u; float f; } c; c.f = f;
    u32 u = c.u;
    return (u16)((u + 0x7fffu + ((u >> 16) & 1u)) >> 16);   // RNE
}
// swizzled u16 index into a [rows][64] bf16 LDS tile
__device__ __forceinline__ int swz(int row, int kbyte) {
    return row * 64 + (((kbyte) ^ ((row & 7) << 4)) >> 1);
}

// ---------------- setup: H0 = masked bf16 x (RUN-major [r][n][64]), esrc fill,
//                  deg zero, pooled zero ----------------
__global__ void k_setup(const float* __restrict__ x, const int* __restrict__ mask,
                        u16* __restrict__ H, int* __restrict__ esrc, int* __restrict__ deg,
                        float* __restrict__ pooled) {
    int id = blockIdx.x * 256 + threadIdx.x;
    if (id < EPAD) esrc[id] = NN;          // dummy -> zero row (pad node NN stays 0)
    if (id < NPAD) deg[id] = 0;
    if (id < 5 * NG * 64) pooled[id] = 0.f;
    if (id < R * NPAD * 16) {              // quads: r, n, q
        int r = id / (NPAD * 16);
        int rem = id - r * (NPAD * 16);
        int n = rem >> 4, q = rem & 15;
        ushort4 o; o.x = o.y = o.z = o.w = 0;
        if (n < NN && mask[r * NN + n] == 0) {
            float4 v = *(const float4*)(x + (size_t)n * 64 + q * 4);
            o.x = f2bf(v.x); o.y = f2bf(v.y); o.z = f2bf(v.z); o.w = f2bf(v.w);
        }
        *(ushort4*)(H + ((size_t)r * NPAD + n) * 64 + q * 4) = o;
    }
}

// ---------------- CSR build ----------------
__global__ void k_deg(const int* __restrict__ dst, int* __restrict__ deg) {
    int e = blockIdx.x * 256 + threadIdx.x;
    if (e < NE) atomicAdd(&deg[dst[e]], 1);
}

// scan of (deg+1 self) padded to x4; writes self edge into first slot
__global__ __launch_bounds__(1024) void k_scan(const int* __restrict__ deg,
                                               int* __restrict__ rowstart,
                                               int* __restrict__ cursor,
                                               int* __restrict__ esrc) {
    __shared__ int wsum[16];
    __shared__ int woff[16];
    __shared__ int carry_s, chunktot;
    const int t = threadIdx.x, lane = t & 63, wv = t >> 6;
    if (t == 0) carry_s = 0;
    __syncthreads();
    for (int base = 0; base < NPAD; base += 1024) {
        int i = base + t;
        int v = (i < NN) ? ((deg[i] + 4) & ~3) : 0;   // (deg+1self) padded to x4
        int x = v;
#pragma unroll
        for (int off = 1; off < 64; off <<= 1) {
            int y = __shfl_up(x, off);
            if (lane >= off) x += y;
        }
        if (lane == 63) wsum[wv] = x;
        __syncthreads();
        if (t < 16) {
            int s = wsum[t], sx = s;
#pragma unroll
            for (int off = 1; off < 16; off <<= 1) {
                int y = __shfl_up(sx, off);
                if (t >= off) sx += y;
            }
            woff[t] = sx - s;
            if (t == 15) chunktot = sx;
        }
        __syncthreads();
        int excl = carry_s + woff[wv] + x - v;
        if (i < NPAD) rowstart[i] = excl;
        if (i < NN) { esrc[excl] = i; cursor[i] = excl + 1; }   // self slot
        __syncthreads();
        if (t == 0) carry_s += chunktot;
        __syncthreads();
    }
    if (t == 0) rowstart[NPAD] = carry_s;
}

__global__ void k_fill(const int* __restrict__ src, const int* __restrict__ dst,
                       int* __restrict__ cursor, int* __restrict__ esrc) {
    int e = blockIdx.x * 256 + threadIdx.x;
    if (e < NE) {
        int p = atomicAdd(&cursor[dst[e]], 1);
        esrc[p] = src[e];
    }
}

// ---------------- fused gather + MFMA-GEMM1 + stat partials (run-XCD-affine) ----
// block -> (run, 32 nodes) via xcd = blk&7, run = xcd&3: each XCD touches ONE
// 2.56MB run slice (fits 4MB per-XCD L2). Each 16-lane group owns ONE node and
// walks its edge list with an 8-deep unrolled body (8 row loads in flight/lane).
__global__ __launch_bounds__(256) void k_fgg(const u16* __restrict__ Z,
                                             u16* __restrict__ Y,
                                             const int* __restrict__ rowstart,
                                             const int* __restrict__ esrc,
                                             const float* __restrict__ W,
                                             const float* __restrict__ bias,
                                             float* __restrict__ part) {
    __shared__ __align__(16) u16 Xs[32 * 64];     // 4 KB
    __shared__ __align__(16) u16 Wt[64 * 64];     // 8 KB
    __shared__ float red[128];
    const int t = threadIdx.x, lane = t & 63, wv = t >> 6;
    const int blk = blockIdx.x;
    const int xcd = blk & 7;
    const int run = xcd & 3;
    const int node0 = ((blk >> 3) + HTILE * (xcd >> 2)) * 32;
    const u16* Zr = Z + (size_t)run * (NPAD * 64);

    {   // stage Wt[n][k] = bf16(W[k][n]) swizzled
        int k = t >> 2, cb = (t & 3) * 16;
        const float* Wp = W + k * 64 + cb;
        float4 v0 = *(const float4*)Wp;
        float4 v1 = *(const float4*)(Wp + 4);
        float4 v2 = *(const float4*)(Wp + 8);
        float4 v3 = *(const float4*)(Wp + 12);
        float vv[16] = {v0.x, v0.y, v0.z, v0.w, v1.x, v1.y, v1.z, v1.w,
                        v2.x, v2.y, v2.z, v2.w, v3.x, v3.y, v3.z, v3.w};
#pragma unroll
        for (int j = 0; j < 16; j++) Wt[swz(cb + j, k * 2)] = f2bf(vv[j]);
    }

    // ---- gather: 16-lane group g owns one node; 8-deep unrolled edge walk ----
    const int g = lane >> 4, cl = (lane & 15) * 4;
#pragma unroll
    for (int i = 0; i < 2; i++) {
        const int n = node0 + wv * 8 + i * 4 + g;   // group's node
        float a0 = 0.f, a1 = 0.f, a2 = 0.f, a3 = 0.f;
        int s0 = rowstart[n];        // uniform within the 16-lane group
        int s1 = rowstart[n + 1];
#define ACC(v) { a0 += bf2f(v.x); a1 += bf2f(v.y); a2 += bf2f(v.z); a3 += bf2f(v.w); }
        int k = s0;
        for (; k + 8 <= s1; k += 8) {
            int4 ia = *(const int4*)(esrc + k);
            int4 ib = *(const int4*)(esrc + k + 4);
            ushort4 w0 = *(const ushort4*)(Zr + (size_t)ia.x * 64 + cl);
            ushort4 w1 = *(const ushort4*)(Zr + (size_t)ia.y * 64 + cl);
            ushort4 w2 = *(const ushort4*)(Zr + (size_t)ia.z * 64 + cl);
            ushort4 w3 = *(const ushort4*)(Zr + (size_t)ia.w * 64 + cl);
            ushort4 w4 = *(const ushort4*)(Zr + (size_t)ib.x * 64 + cl);
            ushort4 w5 = *(const ushort4*)(Zr + (size_t)ib.y * 64 + cl);
            ushort4 w6 = *(const ushort4*)(Zr + (size_t)ib.z * 64 + cl);
            ushort4 w7 = *(const ushort4*)(Zr + (size_t)ib.w * 64 + cl);
            ACC(w0) ACC(w1) ACC(w2) ACC(w3) ACC(w4) ACC(w5) ACC(w6) ACC(w7)
        }
        if (k < s1) {   // exactly 4 remaining (padded to x4)
            int4 ia = *(const int4*)(esrc + k);
            ushort4 w0 = *(const ushort4*)(Zr + (size_t)ia.x * 64 + cl);
            ushort4 w1 = *(const ushort4*)(Zr + (size_t)ia.y * 64 + cl);
            ushort4 w2 = *(const ushort4*)(Zr + (size_t)ia.z * 64 + cl);
            ushort4 w3 = *(const ushort4*)(Zr + (size_t)ia.w * 64 + cl);
            ACC(w0) ACC(w1) ACC(w2) ACC(w3)
        }
#undef ACC
        const int lrow = wv * 8 + i * 4 + g;
        u32 lo = (u32)f2bf(a0) | ((u32)f2bf(a1) << 16);
        u32 hi = (u32)f2bf(a2) | ((u32)f2bf(a3) << 16);
        *(uint2*)&Xs[swz(lrow, cl * 2)] = make_uint2(lo, hi);
    }
    __syncthreads();

    // ---- MFMA: wave = col block wv; both 16-row halves ----
    const int l15 = lane & 15, l4 = lane >> 4;
    const int col = wv * 16 + l15;
    bf16x8 a00 = *(bf16x8*)&Xs[swz(l15, l4 * 16)];
    bf16x8 a01 = *(bf16x8*)&Xs[swz(l15, 64 + l4 * 16)];
    bf16x8 a10 = *(bf16x8*)&Xs[swz(16 + l15, l4 * 16)];
    bf16x8 a11 = *(bf16x8*)&Xs[swz(16 + l15, 64 + l4 * 16)];
    bf16x8 bf0 = *(bf16x8*)&Wt[swz(col, l4 * 16)];
    bf16x8 bf1 = *(bf16x8*)&Wt[swz(col, 64 + l4 * 16)];
    float bv = bias[col];
    f32x4 acc0 = (f32x4){bv, bv, bv, bv};
    f32x4 acc1 = acc0;
    acc0 = __builtin_amdgcn_mfma_f32_16x16x32_bf16(a00, bf0, acc0, 0, 0, 0);
    acc0 = __builtin_amdgcn_mfma_f32_16x16x32_bf16(a01, bf1, acc0, 0, 0, 0);
    acc1 = __builtin_amdgcn_mfma_f32_16x16x32_bf16(a10, bf0, acc1, 0, 0, 0);
    acc1 = __builtin_amdgcn_mfma_f32_16x16x32_bf16(a11, bf1, acc1, 0, 0, 0);

    const size_t ybase = ((size_t)run * NPAD + node0) * 64;
    float s = 0.f, q = 0.f;
#pragma unroll
    for (int j = 0; j < 4; j++) {
        int row0 = l4 * 4 + j, row1 = 16 + l4 * 4 + j;
        __builtin_nontemporal_store(f2bf(acc0[j]), &Y[ybase + (size_t)row0 * 64 + col]);
        __builtin_nontemporal_store(f2bf(acc1[j]), &Y[ybase + (size_t)row1 * 64 + col]);
        float m0 = (node0 + row0 < NN) ? 1.f : 0.f;
        float m1 = (node0 + row1 < NN) ? 1.f : 0.f;
        float v0 = m0 * acc0[j], v1 = m1 * acc1[j];
        s += v0 + v1;
        q += v0 * acc0[j] + v1 * acc1[j];
    }
    s += __shfl_xor(s, 16); s += __shfl_xor(s, 32);
    q += __shfl_xor(q, 16); q += __shfl_xor(q, 32);
    if (l4 == 0) {
        red[wv * 32 + l15] = s;
        red[wv * 32 + 16 + l15] = q;
    }
    __syncthreads();
    if (t < 128) {
        int c = (t < 64) ? t : (t - 64);
        int off = (t < 64) ? 0 : 16;
        part[(size_t)t * NPART + blk] = red[(c >> 4) * 32 + off + (c & 15)];
    }
}

// ---------------- GEMM2: BN+ReLU staging, MFMA, stat partials (64-row blocks) ----
__global__ __launch_bounds__(256) void k_gemm(const u16* __restrict__ Pin,
                                              u16* __restrict__ Qout,
                                              const float* __restrict__ W,
                                              const float* __restrict__ bias,
                                              const float* __restrict__ inStats,
                                              const float* __restrict__ gamma,
                                              const float* __restrict__ beta,
                                              float* __restrict__ part) {
    __shared__ __align__(16) u16 Xs[64 * 64];
    __shared__ __align__(16) u16 Wt[64 * 64];
    __shared__ float red[512];
    __shared__ float Psc[64], Psh[64];
    const int t = threadIdx.x, lane = t & 63, wv = t >> 6;
    const int blk = blockIdx.x;
    const int rblk = blk / (NPAD / 64);               // run
    const int n0 = (blk % (NPAD / 64)) * 64;          // node base

    {   // stage Wt
        int k = t >> 2, cb = (t & 3) * 16;
        const float* Wp = W + k * 64 + cb;
        float4 v0 = *(const float4*)Wp;
        float4 v1 = *(const float4*)(Wp + 4);
        float4 v2 = *(const float4*)(Wp + 8);
        float4 v3 = *(const float4*)(Wp + 12);
        float vv[16] = {v0.x, v0.y, v0.z, v0.w, v1.x, v1.y, v1.z, v1.w,
                        v2.x, v2.y, v2.z, v2.w, v3.x, v3.y, v3.z, v3.w};
#pragma unroll
        for (int j = 0; j < 16; j++) Wt[swz(cb + j, k * 2)] = f2bf(vv[j]);
    }
    if (t < 64) {
        float m = inStats[t] * (1.0f / MROWS);
        float var = inStats[64 + t] * (1.0f / MROWS) - m * m;
        float sc = gamma[t] * rsqrtf(var + BN_EPS);
        Psc[t] = sc;
        Psh[t] = beta[t] - m * sc;
    }
    __syncthreads();

    const int row = t >> 2, cb = (t & 3) * 16;
    const size_t base = ((size_t)rblk * NPAD + n0) * 64;
    {   // stage X, affine+relu, bf16, swizzled
        const u16* Xp = Pin + base + (size_t)row * 64 + cb;
        uint4 a = *(const uint4*)Xp;
        uint4 bq = *(const uint4*)(Xp + 8);
        u32 w[8] = {a.x, a.y, a.z, a.w, bq.x, bq.y, bq.z, bq.w};
        u32 ow[8];
#pragma unroll
        for (int j = 0; j < 8; j++) {
            int c = cb + 2 * j;
            union { u32 u; float f; } lo, hi;
            lo.u = w[j] << 16;
            hi.u = w[j] & 0xffff0000u;
            float v0 = fmaxf(fmaf(lo.f, Psc[c], Psh[c]), 0.f);
            float v1 = fmaxf(fmaf(hi.f, Psc[c + 1], Psh[c + 1]), 0.f);
            ow[j] = (u32)f2bf(v0) | ((u32)f2bf(v1) << 16);
        }
        *(uint4*)&Xs[swz(row, cb * 2)] = make_uint4(ow[0], ow[1], ow[2], ow[3]);
        *(uint4*)&Xs[swz(row, cb * 2 + 16)] = make_uint4(ow[4], ow[5], ow[6], ow[7]);
    }
    __syncthreads();

    const int l4 = lane >> 4, l15 = lane & 15;
    const int arow = wv * 16 + l15;
    bf16x8 af0 = *(bf16x8*)&Xs[swz(arow, l4 * 16)];
    bf16x8 af1 = *(bf16x8*)&Xs[swz(arow, 64 + l4 * 16)];
    f32x4 acc[4];
#pragma unroll
    for (int nb = 0; nb < 4; nb++) {
        int n = nb * 16 + l15;
        float bv = bias[n];
        acc[nb] = (f32x4){bv, bv, bv, bv};
        bf16x8 bf0 = *(bf16x8*)&Wt[swz(n, l4 * 16)];
        bf16x8 bf1 = *(bf16x8*)&Wt[swz(n, 64 + l4 * 16)];
        acc[nb] = __builtin_amdgcn_mfma_f32_16x16x32_bf16(af0, bf0, acc[nb], 0, 0, 0);
        acc[nb] = __builtin_amdgcn_mfma_f32_16x16x32_bf16(af1, bf1, acc[nb], 0, 0, 0);
    }

#pragma unroll
    for (int nb = 0; nb < 4; nb++) {
        int col = nb * 16 + l15;
#pragma unroll
        for (int j = 0; j < 4; j++) {
            int lrow = wv * 16 + l4 * 4 + j;
            __builtin_nontemporal_store(f2bf(acc[nb][j]),
                                        &Qout[base + (size_t)lrow * 64 + col]);
        }
    }

#pragma unroll
    for (int nb = 0; nb < 4; nb++) {
        float s = 0.f, q = 0.f;
#pragma unroll
        for (int j = 0; j < 4; j++) {
            int lrow = wv * 16 + l4 * 4 + j;
            float vm = (n0 + lrow < NN) ? 1.f : 0.f;
            float v = vm * acc[nb][j];
            s += v; q += v * acc[nb][j];
        }
        s += __shfl_xor(s, 16); s += __shfl_xor(s, 32);
        q += __shfl_xor(q, 16); q += __shfl_xor(q, 32);
        if (l4 == 0) {
            red[wv * 128 + nb * 16 + l15] = s;
            red[wv * 128 + 64 + nb * 16 + l15] = q;
        }
    }
    __syncthreads();
    if (t < 128) {
        float v = red[t] + red[128 + t] + red[256 + t] + red[384 + t];
        part[(size_t)t * NPART + blk] = v;
    }
}

// ---------------- reduce stat partials ----------------
__global__ __launch_bounds__(256) void k_statreduce(const float* __restrict__ part,
                                                    float* __restrict__ stats, int count) {
    const int j = blockIdx.x, t = threadIdx.x;
    float s = 0.f;
    for (int p = t; p < count; p += 256) s += part[(size_t)j * NPART + p];
#pragma unroll
    for (int off = 32; off > 0; off >>= 1) s += __shfl_xor(s, off);
    __shared__ float red[4];
    if ((t & 63) == 0) red[t >> 6] = s;
    __syncthreads();
    if (t == 0) stats[j] = red[0] + red[1] + red[2] + red[3];
}

// ---------------- pool: block = (graph, run); BN+ReLU + H materialization ----------------
// (gr*4+r)%8 puts run r on XCDs {r, r+4} — same mapping as k_fgg.
template <bool APPLY>
__global__ __launch_bounds__(256) void k_pool(const u16* __restrict__ Zin,
                                              const int* __restrict__ batch,
                                              float* __restrict__ pooled,
                                              u16* __restrict__ Hout,
                                              const float* __restrict__ stats,
                                              const float* __restrict__ g,
                                              const float* __restrict__ b) {
    const int blk = blockIdx.x;
    const int gr = blk >> 2, r = blk & 3;
    const int t = threadIdx.x;
    int lo = 0, hi = NN;
    while (lo < hi) { int mid = (lo + hi) >> 1; if (batch[mid] < gr) lo = mid + 1; else hi = mid; }
    const int start = lo;
    lo = 0; hi = NN;
    while (lo < hi) { int mid = (lo + hi) >> 1; if (batch[mid] < gr + 1) lo = mid + 1; else hi = mid; }
    const int end = lo;

    const int grp = t >> 4;           // 0..15 node stride
    const int cl = (t & 15) * 4;
    const u16* Zr = Zin + (size_t)r * (NPAD * 64);
    u16* Hr = Hout + (size_t)r * (NPAD * 64);
    float sc[4], sh[4];
    if (APPLY) {
#pragma unroll
        for (int j = 0; j < 4; j++) {
            int c = cl + j;
            float m = stats[c] * (1.f / MROWS);
            float var = stats[64 + c] * (1.f / MROWS) - m * m;
            float s = g[c] * rsqrtf(var + BN_EPS);
            sc[j] = s;
            sh[j] = b[c] - m * s;
        }
    }
    float a0 = 0.f, a1 = 0.f, a2 = 0.f, a3 = 0.f;
#define PBODY(nn)                                                              \
    {                                                                          \
        ushort4 v = *(const ushort4*)(Zr + (size_t)(nn) * 64 + cl);            \
        float f0 = bf2f(v.x), f1 = bf2f(v.y), f2 = bf2f(v.z), f3 = bf2f(v.w);  \
        if (APPLY) {                                                           \
            f0 = fmaxf(fmaf(f0, sc[0], sh[0]), 0.f);                           \
            f1 = fmaxf(fmaf(f1, sc[1], sh[1]), 0.f);                           \
            f2 = fmaxf(fmaf(f2, sc[2], sh[2]), 0.f);                           \
            f3 = fmaxf(fmaf(f3, sc[3], sh[3]), 0.f);                           \
            ushort4 o;                                                         \
            o.x = f2bf(f0); o.y = f2bf(f1); o.z = f2bf(f2); o.w = f2bf(f3);    \
            *(ushort4*)(Hr + (size_t)(nn) * 64 + cl) = o;                      \
        }                                                                      \
        a0 += f0; a1 += f1; a2 += f2; a3 += f3;                                \
    }
    int n = start + grp;
    for (; n + 16 < end; n += 32) { PBODY(n); PBODY(n + 16); }
    for (; n < end; n += 16) PBODY(n);
#undef PBODY
    __shared__ float red[16 * 64];
    red[grp * 64 + cl + 0] = a0;
    red[grp * 64 + cl + 1] = a1;
    red[grp * 64 + cl + 2] = a2;
    red[grp * 64 + cl + 3] = a3;
    __syncthreads();
    if (t < 64) {
        float s = 0.f;
#pragma unroll
        for (int k = 0; k < 16; k++) s += red[k * 64 + t];
        atomicAdd(&pooled[gr * 64 + t], 0.25f * s);
    }
}

// ---------------- readout ----------------
__global__ __launch_bounds__(256) void k_readout(const float* __restrict__ pooled,
                                                 const float* __restrict__ fcW,
                                                 const float* __restrict__ fcb,
                                                 float* __restrict__ out) {
    const int gr = blockIdx.x, t = threadIdx.x;
    const int c = t & 15, seg = t >> 4;
    float acc = 0.f;
#pragma unroll
    for (int i = 0; i < 5; i++)
#pragma unroll
        for (int k = 0; k < 4; k++) {
            int d = seg * 4 + k;
            acc = fmaf(pooled[i * (NG * D) + gr * D + d], fcW[i * 1024 + d * 16 + c], acc);
        }
    __shared__ float red[16][17];
    red[seg][c] = acc;
    __syncthreads();
    if (t < 16) {
        float s = 0.f;
#pragma unroll
        for (int s2 = 0; s2 < 16; s2++) s += red[s2][t];
#pragma unroll
        for (int i = 0; i < 5; i++) s += fcb[i * NC + t];
        float mx = s;
#pragma unroll
        for (int m = 1; m < 16; m <<= 1) mx = fmaxf(mx, __shfl_xor(mx, m));
        float e = expf(s - mx), se = e;
#pragma unroll
        for (int m = 1; m < 16; m <<= 1) se += __shfl_xor(se, m);
        out[gr * NC + t] = s - mx - logf(se);
    }
}

extern "C" void kernel_launch(void* const* d_in, const int* in_sizes, int n_in,
                              void* d_out, int out_size, void* d_ws, size_t ws_size,
                              hipStream_t stream) {
    const float* x = (const float*)d_in[0];
    const int* ei = (const int*)d_in[1];
    const int* srcp = ei;
    const int* dstp = ei + NE;
    const int* batch = (const int*)d_in[2];
    const int* mask = (const int*)d_in[3];
    const float* convW1 = (const float*)d_in[4];
    const float* convb1 = (const float*)d_in[5];
    const float* mlp_bn_g = (const float*)d_in[6];
    const float* mlp_bn_b = (const float*)d_in[7];
    const float* convW2 = (const float*)d_in[8];
    const float* convb2 = (const float*)d_in[9];
    const float* bn_g = (const float*)d_in[10];
    const float* bn_b = (const float*)d_in[11];
    const float* fcW = (const float*)d_in[12];
    const float* fcb = (const float*)d_in[13];
    float* out = (float*)d_out;

    u16* H = (u16*)d_ws;                       // [R][NPAD][64] bf16 (pad rows stay zero)
    u16* P = H + (size_t)R * NPAD * 64;
    u16* Q = P + (size_t)R * NPAD * 64;
    float* pooled = (float*)(Q + (size_t)R * NPAD * 64);   // [5][NG][64]
    float* stats = pooled + 5 * NG * D;        // [NL][2][128]
    float* part = stats + NL * 2 * 128;        // [128][NPART]
    int* rowstart = (int*)(part + 128 * NPART);  // [NPAD+1]
    int* cursor = rowstart + NPAD + 1;           // [NN]
    int* deg = cursor + NPAD;                    // [NPAD]
    int* esrc = deg + NPAD;                      // [EPAD]

    k_setup<<<(R * NPAD * 16 + 255) / 256, 256, 0, stream>>>(x, mask, H, esrc, deg, pooled);
    k_deg<<<(NE + 255) / 256, 256, 0, stream>>>(dstp, deg);
    k_scan<<<1, 1024, 0, stream>>>(deg, rowstart, cursor, esrc);
    k_fill<<<(NE + 255) / 256, 256, 0, stream>>>(srcp, dstp, cursor, esrc);

    k_pool<false><<<NPOOL, 256, 0, stream>>>(H, batch, pooled, nullptr,
                                             nullptr, nullptr, nullptr);

    for (int i = 0; i < NL; i++) {
        float* st1 = stats + (i * 2 + 0) * 128;
        float* st2 = stats + (i * 2 + 1) * 128;
        k_fgg<<<NBLKF, 256, 0, stream>>>(H, P, rowstart, esrc,
                                         convW1 + i * 4096, convb1 + i * 64, part);
        k_statreduce<<<128, 256, 0, stream>>>(part, st1, NBLKF);
        k_gemm<<<NBLKG, 256, 0, stream>>>(P, Q, convW2 + i * 4096, convb2 + i * 64,
                                          st1, mlp_bn_g + i * 64, mlp_bn_b + i * 64, part);
        k_statreduce<<<128, 256, 0, stream>>>(part, st2, NBLKG);
        k_pool<true><<<NPOOL, 256, 0, stream>>>(Q, batch, pooled + (i + 1) * (NG * D), H,
                                                st2, bn_g + i * 64, bn_b + i * 64);
    }

    k_readout<<<NG, 256, 0, stream>>>(pooled, fcW, fcb, out);
}

// Round 13
// 310.386 us; speedup vs baseline: 1.1463x; 1.0447x over previous
//
#include <hip/hip_runtime.h>

typedef unsigned short u16;
typedef unsigned int u32;
typedef __attribute__((ext_vector_type(8))) short bf16x8;
typedef __attribute__((ext_vector_type(4))) float f32x4;

#define NN 20000      // real nodes
#define NE 320000     // edges
#define NPAD 20032    // nodes padded (x64)
#define D 64
#define R 4
#define NG 128
#define NC 16
#define NL 4
#define MROWS (NN*R)        // BN divisor (real rows only)
#define NBLKF (NPAD/8)      // 2504 fgg blocks (8 nodes = 32 rows each)
#define NBLKG (NPAD/16)     // 1252 gemm blocks (16 nodes = 64 rows each)
#define NPART NBLKF         // part stride
#define NPOOL (4*NG)        // 512 pool blocks
#define EPAD 480256         // padded edge slots (>= NE + 4*NN)
#define BN_EPS 1e-5f

__device__ __forceinline__ float bf2f(u16 v) {
    union { u32 u; float f; } c; c.u = ((u32)v) << 16; return c.f;
}
__device__ __forceinline__ u16 f2bf(float f) {
    union { u32 u; float f; } c; c.f = f;
    u32 u = c.u;
    return (u16)((u + 0x7fffu + ((u >> 16) & 1u)) >> 16);   // RNE
}
// swizzled u16 index into a [rows][64] bf16 LDS tile
__device__ __forceinline__ int swz(int row, int kbyte) {
    return row * 64 + (((kbyte) ^ ((row & 7) << 4)) >> 1);
}

// ---------------- setup: H0 = masked bf16 x (node-major [n][r][64]), esrc fill,
//                  deg zero, pooled zero ----------------
__global__ void k_setup(const float* __restrict__ x, const int* __restrict__ mask,
                        u16* __restrict__ H, int* __restrict__ esrc, int* __restrict__ deg,
                        float* __restrict__ pooled) {
    int id = blockIdx.x * 256 + threadIdx.x;
    if (id < EPAD) esrc[id] = NN;          // dummy -> zero row (node NN is padded, stays 0)
    if (id < NPAD) deg[id] = 0;
    if (id < 5 * NG * 64) pooled[id] = 0.f;
    if (id < NPAD * 64) {                  // ushort4 quads: n, r, q
        int n = id >> 6, r = (id >> 4) & 3, q = id & 15;
        ushort4 o; o.x = o.y = o.z = o.w = 0;
        if (n < NN && mask[r * NN + n] == 0) {
            float4 v = *(const float4*)(x + (size_t)n * 64 + q * 4);
            o.x = f2bf(v.x); o.y = f2bf(v.y); o.z = f2bf(v.z); o.w = f2bf(v.w);
        }
        *(ushort4*)(H + ((size_t)n * 4 + r) * 64 + q * 4) = o;
    }
}

// ---------------- CSR build ----------------
__global__ void k_deg(const int* __restrict__ dst, int* __restrict__ deg) {
    int e = blockIdx.x * 256 + threadIdx.x;
    if (e < NE) atomicAdd(&deg[dst[e]], 1);
}

// scan of (deg+1 self) padded to x4; writes self edge into first slot
__global__ __launch_bounds__(1024) void k_scan(const int* __restrict__ deg,
                                               int* __restrict__ rowstart,
                                               int* __restrict__ cursor,
                                               int* __restrict__ esrc) {
    __shared__ int wsum[16];
    __shared__ int woff[16];
    __shared__ int carry_s, chunktot;
    const int t = threadIdx.x, lane = t & 63, wv = t >> 6;
    if (t == 0) carry_s = 0;
    __syncthreads();
    for (int base = 0; base < NPAD; base += 1024) {
        int i = base + t;
        int v = (i < NN) ? ((deg[i] + 4) & ~3) : 0;   // (deg+1self) padded to x4
        int x = v;
#pragma unroll
        for (int off = 1; off < 64; off <<= 1) {
            int y = __shfl_up(x, off);
            if (lane >= off) x += y;
        }
        if (lane == 63) wsum[wv] = x;
        __syncthreads();
        if (t < 16) {
            int s = wsum[t], sx = s;
#pragma unroll
            for (int off = 1; off < 16; off <<= 1) {
                int y = __shfl_up(sx, off);
                if (t >= off) sx += y;
            }
            woff[t] = sx - s;
            if (t == 15) chunktot = sx;
        }
        __syncthreads();
        int excl = carry_s + woff[wv] + x - v;
        if (i < NPAD) rowstart[i] = excl;
        if (i < NN) { esrc[excl] = i; cursor[i] = excl + 1; }   // self slot
        __syncthreads();
        if (t == 0) carry_s += chunktot;
        __syncthreads();
    }
    if (t == 0) rowstart[NPAD] = carry_s;
}

__global__ void k_fill(const int* __restrict__ src, const int* __restrict__ dst,
                       int* __restrict__ cursor, int* __restrict__ esrc) {
    int e = blockIdx.x * 256 + threadIdx.x;
    if (e < NE) {
        int p = atomicAdd(&cursor[dst[e]], 1);
        esrc[p] = src[e];
    }
}

// ---------------- fused gather + MFMA-GEMM1 + stat partials ----------------
// block = 8 nodes = 32 rows (node-major [n][r][64], 512B rows). Wave gathers 2 nodes
// (pure bf16 adds, self+dummy in padded stream), one barrier, 32x64 MFMA tile.
__global__ __launch_bounds__(256) void k_fgg(const u16* __restrict__ Z,
                                             u16* __restrict__ Y,
                                             const int* __restrict__ rowstart,
                                             const int* __restrict__ esrc,
                                             const float* __restrict__ W,
                                             const float* __restrict__ bias,
                                             float* __restrict__ part) {
    __shared__ __align__(16) u16 Xs[32 * 64];     // 4 KB
    __shared__ __align__(16) u16 Wt[64 * 64];     // 8 KB
    __shared__ float red[128];
    const int t = threadIdx.x, lane = t & 63, wv = t >> 6;
    const int blk = blockIdx.x;
    const int node0 = blk * 8;

    {   // stage Wt[n][k] = bf16(W[k][n]) swizzled
        int k = t >> 2, cb = (t & 3) * 16;
        const float* Wp = W + k * 64 + cb;
        float4 v0 = *(const float4*)Wp;
        float4 v1 = *(const float4*)(Wp + 4);
        float4 v2 = *(const float4*)(Wp + 8);
        float4 v3 = *(const float4*)(Wp + 12);
        float vv[16] = {v0.x, v0.y, v0.z, v0.w, v1.x, v1.y, v1.z, v1.w,
                        v2.x, v2.y, v2.z, v2.w, v3.x, v3.y, v3.z, v3.w};
#pragma unroll
        for (int j = 0; j < 16; j++) Wt[swz(cb + j, k * 2)] = f2bf(vv[j]);
    }

    // ---- gather: lane covers (run rr, cols cl..cl+3); wave does 2 nodes ----
    const int rr = lane >> 4, cl = (lane & 15) * 4;
#pragma unroll
    for (int i = 0; i < 2; i++) {
        const int n = node0 + wv * 2 + i;
        float a0 = 0.f, a1 = 0.f, a2 = 0.f, a3 = 0.f;
        int s0 = __builtin_amdgcn_readfirstlane(rowstart[n]);
        int s1 = __builtin_amdgcn_readfirstlane(rowstart[n + 1]);
#define ACC(v) { a0 += bf2f(v.x); a1 += bf2f(v.y); a2 += bf2f(v.z); a3 += bf2f(v.w); }
        int k = s0;
        for (; k + 8 <= s1; k += 8) {
            int4 ia = *(const int4*)(esrc + k);
            int4 ib = *(const int4*)(esrc + k + 4);
            ushort4 w0 = *(const ushort4*)(Z + (size_t)ia.x * 256 + lane * 4);
            ushort4 w1 = *(const ushort4*)(Z + (size_t)ia.y * 256 + lane * 4);
            ushort4 w2 = *(const ushort4*)(Z + (size_t)ia.z * 256 + lane * 4);
            ushort4 w3 = *(const ushort4*)(Z + (size_t)ia.w * 256 + lane * 4);
            ushort4 w4 = *(const ushort4*)(Z + (size_t)ib.x * 256 + lane * 4);
            ushort4 w5 = *(const ushort4*)(Z + (size_t)ib.y * 256 + lane * 4);
            ushort4 w6 = *(const ushort4*)(Z + (size_t)ib.z * 256 + lane * 4);
            ushort4 w7 = *(const ushort4*)(Z + (size_t)ib.w * 256 + lane * 4);
            ACC(w0) ACC(w1) ACC(w2) ACC(w3) ACC(w4) ACC(w5) ACC(w6) ACC(w7)
        }
        if (k < s1) {   // exactly 4 remaining (padded to x4)
            int4 ia = *(const int4*)(esrc + k);
            ushort4 w0 = *(const ushort4*)(Z + (size_t)ia.x * 256 + lane * 4);
            ushort4 w1 = *(const ushort4*)(Z + (size_t)ia.y * 256 + lane * 4);
            ushort4 w2 = *(const ushort4*)(Z + (size_t)ia.z * 256 + lane * 4);
            ushort4 w3 = *(const ushort4*)(Z + (size_t)ia.w * 256 + lane * 4);
            ACC(w0) ACC(w1) ACC(w2) ACC(w3)
        }
#undef ACC
        const int lrow = (wv * 2 + i) * 4 + rr;
        u32 lo = (u32)f2bf(a0) | ((u32)f2bf(a1) << 16);
        u32 hi = (u32)f2bf(a2) | ((u32)f2bf(a3) << 16);
        *(uint2*)&Xs[swz(lrow, cl * 2)] = make_uint2(lo, hi);
    }
    __syncthreads();

    // ---- MFMA: wave = col block wv; both 16-row halves ----
    const int l15 = lane & 15, l4 = lane >> 4;
    const int col = wv * 16 + l15;
    bf16x8 a00 = *(bf16x8*)&Xs[swz(l15, l4 * 16)];
    bf16x8 a01 = *(bf16x8*)&Xs[swz(l15, 64 + l4 * 16)];
    bf16x8 a10 = *(bf16x8*)&Xs[swz(16 + l15, l4 * 16)];
    bf16x8 a11 = *(bf16x8*)&Xs[swz(16 + l15, 64 + l4 * 16)];
    bf16x8 bf0 = *(bf16x8*)&Wt[swz(col, l4 * 16)];
    bf16x8 bf1 = *(bf16x8*)&Wt[swz(col, 64 + l4 * 16)];
    float bv = bias[col];
    f32x4 acc0 = (f32x4){bv, bv, bv, bv};
    f32x4 acc1 = acc0;
    acc0 = __builtin_amdgcn_mfma_f32_16x16x32_bf16(a00, bf0, acc0, 0, 0, 0);
    acc0 = __builtin_amdgcn_mfma_f32_16x16x32_bf16(a01, bf1, acc0, 0, 0, 0);
    acc1 = __builtin_amdgcn_mfma_f32_16x16x32_bf16(a10, bf0, acc1, 0, 0, 0);
    acc1 = __builtin_amdgcn_mfma_f32_16x16x32_bf16(a11, bf1, acc1, 0, 0, 0);

    const size_t ybase = (size_t)node0 * 4 * 64;
    float s = 0.f, q = 0.f;
#pragma unroll
    for (int j = 0; j < 4; j++) {
        int row0 = l4 * 4 + j, row1 = 16 + l4 * 4 + j;
        Y[ybase + (size_t)row0 * 64 + col] = f2bf(acc0[j]);
        Y[ybase + (size_t)row1 * 64 + col] = f2bf(acc1[j]);
        float m0 = (node0 + (row0 >> 2) < NN) ? 1.f : 0.f;
        float m1 = (node0 + (row1 >> 2) < NN) ? 1.f : 0.f;
        float v0 = m0 * acc0[j], v1 = m1 * acc1[j];
        s += v0 + v1;
        q += v0 * acc0[j] + v1 * acc1[j];
    }
    s += __shfl_xor(s, 16); s += __shfl_xor(s, 32);
    q += __shfl_xor(q, 16); q += __shfl_xor(q, 32);
    if (l4 == 0) {
        red[wv * 32 + l15] = s;
        red[wv * 32 + 16 + l15] = q;
    }
    __syncthreads();
    if (t < 128) {
        int c = (t < 64) ? t : (t - 64);
        int off = (t < 64) ? 0 : 16;
        part[(size_t)t * NPART + blk] = red[(c >> 4) * 32 + off + (c & 15)];
    }
}

// ---------------- GEMM2: BN+ReLU staging, MFMA, stat partials (64-row blocks) ----
__global__ __launch_bounds__(256) void k_gemm(const u16* __restrict__ Pin,
                                              u16* __restrict__ Qout,
                                              const float* __restrict__ W,
                                              const float* __restrict__ bias,
                                              const float* __restrict__ inStats,
                                              const float* __restrict__ gamma,
                                              const float* __restrict__ beta,
                                              float* __restrict__ part) {
    __shared__ __align__(16) u16 Xs[64 * 64];
    __shared__ __align__(16) u16 Wt[64 * 64];
    __shared__ float red[512];
    __shared__ float Psc[64], Psh[64];
    const int t = threadIdx.x, lane = t & 63, wv = t >> 6;
    const int blk = blockIdx.x;
    const int m0 = blk * 64;            // row base (row = node*4 + run)

    {   // stage Wt
        int k = t >> 2, cb = (t & 3) * 16;
        const float* Wp = W + k * 64 + cb;
        float4 v0 = *(const float4*)Wp;
        float4 v1 = *(const float4*)(Wp + 4);
        float4 v2 = *(const float4*)(Wp + 8);
        float4 v3 = *(const float4*)(Wp + 12);
        float vv[16] = {v0.x, v0.y, v0.z, v0.w, v1.x, v1.y, v1.z, v1.w,
                        v2.x, v2.y, v2.z, v2.w, v3.x, v3.y, v3.z, v3.w};
#pragma unroll
        for (int j = 0; j < 16; j++) Wt[swz(cb + j, k * 2)] = f2bf(vv[j]);
    }
    if (t < 64) {
        float m = inStats[t] * (1.0f / MROWS);
        float var = inStats[64 + t] * (1.0f / MROWS) - m * m;
        float sc = gamma[t] * rsqrtf(var + BN_EPS);
        Psc[t] = sc;
        Psh[t] = beta[t] - m * sc;
    }
    __syncthreads();

    const int row = t >> 2, cb = (t & 3) * 16;
    const size_t base = (size_t)m0 * 64;
    {   // stage X, affine+relu, bf16, swizzled
        const u16* Xp = Pin + base + (size_t)row * 64 + cb;
        uint4 a = *(const uint4*)Xp;
        uint4 bq = *(const uint4*)(Xp + 8);
        u32 w[8] = {a.x, a.y, a.z, a.w, bq.x, bq.y, bq.z, bq.w};
        u32 ow[8];
#pragma unroll
        for (int j = 0; j < 8; j++) {
            int c = cb + 2 * j;
            union { u32 u; float f; } lo, hi;
            lo.u = w[j] << 16;
            hi.u = w[j] & 0xffff0000u;
            float v0 = fmaxf(fmaf(lo.f, Psc[c], Psh[c]), 0.f);
            float v1 = fmaxf(fmaf(hi.f, Psc[c + 1], Psh[c + 1]), 0.f);
            ow[j] = (u32)f2bf(v0) | ((u32)f2bf(v1) << 16);
        }
        *(uint4*)&Xs[swz(row, cb * 2)] = make_uint4(ow[0], ow[1], ow[2], ow[3]);
        *(uint4*)&Xs[swz(row, cb * 2 + 16)] = make_uint4(ow[4], ow[5], ow[6], ow[7]);
    }
    __syncthreads();

    const int l4 = lane >> 4, l15 = lane & 15;
    const int arow = wv * 16 + l15;
    bf16x8 af0 = *(bf16x8*)&Xs[swz(arow, l4 * 16)];
    bf16x8 af1 = *(bf16x8*)&Xs[swz(arow, 64 + l4 * 16)];
    f32x4 acc[4];
#pragma unroll
    for (int n0 = 0; n0 < 4; n0++) {
        int n = n0 * 16 + l15;
        float bv = bias[n];
        acc[n0] = (f32x4){bv, bv, bv, bv};
        bf16x8 bf0 = *(bf16x8*)&Wt[swz(n, l4 * 16)];
        bf16x8 bf1 = *(bf16x8*)&Wt[swz(n, 64 + l4 * 16)];
        acc[n0] = __builtin_amdgcn_mfma_f32_16x16x32_bf16(af0, bf0, acc[n0], 0, 0, 0);
        acc[n0] = __builtin_amdgcn_mfma_f32_16x16x32_bf16(af1, bf1, acc[n0], 0, 0, 0);
    }

#pragma unroll
    for (int n0 = 0; n0 < 4; n0++) {
        int col = n0 * 16 + l15;
#pragma unroll
        for (int j = 0; j < 4; j++) {
            int lrow = wv * 16 + l4 * 4 + j;
            Qout[base + (size_t)lrow * 64 + col] = f2bf(acc[n0][j]);
        }
    }

#pragma unroll
    for (int n0 = 0; n0 < 4; n0++) {
        float s = 0.f, q = 0.f;
#pragma unroll
        for (int j = 0; j < 4; j++) {
            int lrow = wv * 16 + l4 * 4 + j;
            float vm = (((m0 + lrow) >> 2) < NN) ? 1.f : 0.f;
            float v = vm * acc[n0][j];
            s += v; q += v * acc[n0][j];
        }
        s += __shfl_xor(s, 16); s += __shfl_xor(s, 32);
        q += __shfl_xor(q, 16); q += __shfl_xor(q, 32);
        if (l4 == 0) {
            red[wv * 128 + n0 * 16 + l15] = s;
            red[wv * 128 + 64 + n0 * 16 + l15] = q;
        }
    }
    __syncthreads();
    if (t < 128) {
        float v = red[t] + red[128 + t] + red[256 + t] + red[384 + t];
        part[(size_t)t * NPART + blk] = v;
    }
}

// ---------------- reduce stat partials ----------------
__global__ __launch_bounds__(256) void k_statreduce(const float* __restrict__ part,
                                                    float* __restrict__ stats, int count) {
    const int j = blockIdx.x, t = threadIdx.x;
    float s = 0.f;
    for (int p = t; p < count; p += 256) s += part[(size_t)j * NPART + p];
#pragma unroll
    for (int off = 32; off > 0; off >>= 1) s += __shfl_xor(s, off);
    __shared__ float red[4];
    if ((t & 63) == 0) red[t >> 6] = s;
    __syncthreads();
    if (t == 0) stats[j] = red[0] + red[1] + red[2] + red[3];
}

// ---------------- pool: block = (graph, run); BN+ReLU + H materialization ----------------
template <bool APPLY>
__global__ __launch_bounds__(256) void k_pool(const u16* __restrict__ Zin,
                                              const int* __restrict__ batch,
                                              float* __restrict__ pooled,
                                              u16* __restrict__ Hout,
                                              const float* __restrict__ stats,
                                              const float* __restrict__ g,
                                              const float* __restrict__ b) {
    const int blk = blockIdx.x;
    const int gr = blk >> 2, r = blk & 3;
    const int t = threadIdx.x, lane = t & 63, wv = t >> 6;
    int lo = 0, hi = NN;
    while (lo < hi) { int mid = (lo + hi) >> 1; if (batch[mid] < gr) lo = mid + 1; else hi = mid; }
    const int start = lo;
    lo = 0; hi = NN;
    while (lo < hi) { int mid = (lo + hi) >> 1; if (batch[mid] < gr + 1) lo = mid + 1; else hi = mid; }
    const int end = lo;

    float sc = 1.f, sh = 0.f;
    if (APPLY) {
        float m = stats[lane] * (1.f / MROWS);
        float var = stats[64 + lane] * (1.f / MROWS) - m * m;
        sc = g[lane] * rsqrtf(var + BN_EPS);
        sh = b[lane] - m * sc;
    }
    float acc = 0.f;
#define PBODY(nn)                                                              \
    {                                                                          \
        float f = bf2f(Zin[((size_t)(nn) * 4 + r) * 64 + lane]);               \
        if (APPLY) {                                                           \
            f = fmaxf(fmaf(f, sc, sh), 0.f);                                   \
            Hout[((size_t)(nn) * 4 + r) * 64 + lane] = f2bf(f);                \
        }                                                                      \
        acc += f;                                                              \
    }
    int n = start + wv;
    for (; n + 12 < end; n += 16) { PBODY(n); PBODY(n + 4); PBODY(n + 8); PBODY(n + 12); }
    for (; n < end; n += 4) PBODY(n);
#undef PBODY
    __shared__ float red[4][64];
    red[wv][lane] = acc;
    __syncthreads();
    if (t < 64) {
        float s = red[0][t] + red[1][t] + red[2][t] + red[3][t];
        atomicAdd(&pooled[gr * 64 + t], 0.25f * s);
    }
}

// ---------------- readout ----------------
__global__ __launch_bounds__(256) void k_readout(const float* __restrict__ pooled,
                                                 const float* __restrict__ fcW,
                                                 const float* __restrict__ fcb,
                                                 float* __restrict__ out) {
    const int gr = blockIdx.x, t = threadIdx.x;
    const int c = t & 15, seg = t >> 4;
    float acc = 0.f;
#pragma unroll
    for (int i = 0; i < 5; i++)
#pragma unroll
        for (int k = 0; k < 4; k++) {
            int d = seg * 4 + k;
            acc = fmaf(pooled[i * (NG * D) + gr * D + d], fcW[i * 1024 + d * 16 + c], acc);
        }
    __shared__ float red[16][17];
    red[seg][c] = acc;
    __syncthreads();
    if (t < 16) {
        float s = 0.f;
#pragma unroll
        for (int s2 = 0; s2 < 16; s2++) s += red[s2][t];
#pragma unroll
        for (int i = 0; i < 5; i++) s += fcb[i * NC + t];
        float mx = s;
#pragma unroll
        for (int m = 1; m < 16; m <<= 1) mx = fmaxf(mx, __shfl_xor(mx, m));
        float e = expf(s - mx), se = e;
#pragma unroll
        for (int m = 1; m < 16; m <<= 1) se += __shfl_xor(se, m);
        out[gr * NC + t] = s - mx - logf(se);
    }
}

extern "C" void kernel_launch(void* const* d_in, const int* in_sizes, int n_in,
                              void* d_out, int out_size, void* d_ws, size_t ws_size,
                              hipStream_t stream) {
    const float* x = (const float*)d_in[0];
    const int* ei = (const int*)d_in[1];
    const int* srcp = ei;
    const int* dstp = ei + NE;
    const int* batch = (const int*)d_in[2];
    const int* mask = (const int*)d_in[3];
    const float* convW1 = (const float*)d_in[4];
    const float* convb1 = (const float*)d_in[5];
    const float* mlp_bn_g = (const float*)d_in[6];
    const float* mlp_bn_b = (const float*)d_in[7];
    const float* convW2 = (const float*)d_in[8];
    const float* convb2 = (const float*)d_in[9];
    const float* bn_g = (const float*)d_in[10];
    const float* bn_b = (const float*)d_in[11];
    const float* fcW = (const float*)d_in[12];
    const float* fcb = (const float*)d_in[13];
    float* out = (float*)d_out;

    u16* H = (u16*)d_ws;                       // [NPAD][4][64] bf16 (pad rows stay zero)
    u16* P = H + (size_t)NPAD * 256;
    u16* Q = P + (size_t)NPAD * 256;
    float* pooled = (float*)(Q + (size_t)NPAD * 256);   // [5][NG][64]
    float* stats = pooled + 5 * NG * D;        // [NL][2][128]
    float* part = stats + NL * 2 * 128;        // [128][NPART]
    int* rowstart = (int*)(part + 128 * NPART);  // [NPAD+1]
    int* cursor = rowstart + NPAD + 1;           // [NN]
    int* deg = cursor + NPAD;                    // [NPAD]
    int* esrc = deg + NPAD;                      // [EPAD]

    k_setup<<<(NPAD * 64 + 255) / 256, 256, 0, stream>>>(x, mask, H, esrc, deg, pooled);
    k_deg<<<(NE + 255) / 256, 256, 0, stream>>>(dstp, deg);
    k_scan<<<1, 1024, 0, stream>>>(deg, rowstart, cursor, esrc);
    k_fill<<<(NE + 255) / 256, 256, 0, stream>>>(srcp, dstp, cursor, esrc);

    k_pool<false><<<NPOOL, 256, 0, stream>>>(H, batch, pooled, nullptr,
                                             nullptr, nullptr, nullptr);

    for (int i = 0; i < NL; i++) {
        float* st1 = stats + (i * 2 + 0) * 128;
        float* st2 = stats + (i * 2 + 1) * 128;
        k_fgg<<<NBLKF, 256, 0, stream>>>(H, P, rowstart, esrc,
                                         convW1 + i * 4096, convb1 + i * 64, part);
        k_statreduce<<<128, 256, 0, stream>>>(part, st1, NBLKF);
        k_gemm<<<NBLKG, 256, 0, stream>>>(P, Q, convW2 + i * 4096, convb2 + i * 64,
                                          st1, mlp_bn_g + i * 64, mlp_bn_b + i * 64, part);
        k_statreduce<<<128, 256, 0, stream>>>(part, st2, NBLKG);
        k_pool<true><<<NPOOL, 256, 0, stream>>>(Q, batch, pooled + (i + 1) * (NG * D), H,
                                                st2, bn_g + i * 64, bn_b + i * 64);
    }

    k_readout<<<NG, 256, 0, stream>>>(pooled, fcW, fcb, out);
}